// Round 3
// baseline (1174.493 us; speedup 1.0000x reference)
//
#include <hip/hip_runtime.h>
#include <stdint.h>

// Problem constants
#define B_    32
#define T_    256
#define CD    100
#define BD    100
#define TD    20
#define LIN   200
#define HD    200
#define INDIM 420
#define G4    800   // 4*H

typedef __attribute__((ext_vector_type(8))) short bfrag8;   // 8 bf16 (4 VGPRs)
typedef __attribute__((ext_vector_type(4))) float f32x4v;   // MFMA accumulator

static __device__ __forceinline__ unsigned short f2bf(float f) {
  unsigned u = __float_as_uint(f);
  u = u + 0x7fffu + ((u >> 16) & 1u);   // RTNE
  return (unsigned short)(u >> 16);
}
static __device__ __forceinline__ float bf2f(unsigned short s) {
  return __uint_as_float(((unsigned)s) << 16);
}
static __device__ __forceinline__ float sigm(float x) {
  return __builtin_amdgcn_rcpf(1.0f + __builtin_amdgcn_exp2f(x * -1.4426950408889634f));
}
static __device__ __forceinline__ float tanhx(float x) {
  return 1.0f - 2.0f * __builtin_amdgcn_rcpf(1.0f + __builtin_amdgcn_exp2f(x * 2.8853900817779268f));
}

static __device__ __forceinline__ void mk_hilo(float4 a, float4 b, bfrag8& hi, bfrag8& lo) {
  float q[8] = {a.x, a.y, a.z, a.w, b.x, b.y, b.z, b.w};
  #pragma unroll
  for (int j = 0; j < 8; ++j) {
    unsigned short h = f2bf(q[j]);
    hi[j] = (short)h;
    lo[j] = (short)f2bf(q[j] - bf2f(h));
  }
}
static __device__ __forceinline__ bfrag8 mk_hi(float4 a, float4 b) {
  bfrag8 r;
  float q[8] = {a.x, a.y, a.z, a.w, b.x, b.y, b.z, b.w};
  #pragma unroll
  for (int j = 0; j < 8; ++j) r[j] = (short)f2bf(q[j]);
  return r;
}

// ---------------------------------------------------------------------------
// Kernel W: pre-split fc_w and Wih_{l,r} into hi/lo bf16 in MFMA fragment layout
// frag layout: elem i = ((nt*KT + kt)*64 + lane)*8 + j ;
//   n = nt*16 + (lane&15), k = kt*32 + (lane>>4)*8 + j
// Wih rows are PERMUTED: frag col n' maps to original row (n'&3)*200 + (n'>>2)
// ---------------------------------------------------------------------------
__global__ void presplit_kernel(const float* __restrict__ fc_w,
                                const float* __restrict__ Wih_l,
                                const float* __restrict__ Wih_r,
                                unsigned short* __restrict__ fcw_hi,
                                unsigned short* __restrict__ fcw_lo,
                                unsigned short* __restrict__ wih_hi,
                                unsigned short* __restrict__ wih_lo) {
  int tid = blockIdx.x * blockDim.x + threadIdx.x;
  int stride = gridDim.x * blockDim.x;
  for (int i = tid; i < 13 * 14 * 512; i += stride) {
    int j = i & 7, l = (i >> 3) & 63, f = i >> 9;
    int kt = f % 14, nt = f / 14;
    int n = nt * 16 + (l & 15);
    int k = kt * 32 + ((l >> 4) << 3) + j;
    float v = (n < LIN && k < INDIM) ? fc_w[n * INDIM + k] : 0.0f;
    unsigned short h = f2bf(v);
    fcw_hi[i] = h;
    fcw_lo[i] = f2bf(v - bf2f(h));
  }
  for (int d = 0; d < 2; ++d) {
    const float* W = d ? Wih_r : Wih_l;
    unsigned short* oh = wih_hi + (size_t)d * 179200;
    unsigned short* ol = wih_lo + (size_t)d * 179200;
    for (int i = tid; i < 50 * 7 * 512; i += stride) {
      int j = i & 7, l = (i >> 3) & 63, f = i >> 9;
      int kt = f % 7, nt = f / 7;
      int np = nt * 16 + (l & 15);                 // permuted col n'
      int no = (np & 3) * 200 + (np >> 2);         // original Wih row
      int k = kt * 32 + ((l >> 4) << 3) + j;
      float v = (k < LIN) ? W[no * LIN + k] : 0.0f;
      unsigned short h = f2bf(v);
      oh[i] = h;
      ol[i] = f2bf(v - bf2f(h));
    }
  }
}

// ---------------------------------------------------------------------------
// Kernel A: embedding gather + concat(420) + FC + tanh -> x [2*8192][200] f32
// ---------------------------------------------------------------------------
__global__ __launch_bounds__(256) void fc_kernel(
    const int* __restrict__ chars, const int* __restrict__ left_bichar,
    const int* __restrict__ right_bichar, const int* __restrict__ extchars,
    const int* __restrict__ extleft, const int* __restrict__ extright,
    const int* __restrict__ ctype,
    const float* __restrict__ E_char, const float* __restrict__ E_extchar,
    const float* __restrict__ E_bichar, const float* __restrict__ E_extbichar,
    const float* __restrict__ E_ctype, const float* __restrict__ fc_b,
    const unsigned short* __restrict__ fcw_hi, const unsigned short* __restrict__ fcw_lo,
    float* __restrict__ x) {
  __shared__ __align__(16) float feat[32 * 452];
  int rb = blockIdx.x;            // dir*256 + t
  int dir = rb >> 8;
  int t = rb & 255;
  int tid = threadIdx.x;
  const int* bi  = dir ? right_bichar : left_bichar;
  const int* ebi = dir ? extright : extleft;

  for (int cc = tid; cc < 32 * 113; cc += 256) {
    int lr = cc / 113, kc = cc - lr * 113;
    int k = kc << 2;
    float4 v = make_float4(0.f, 0.f, 0.f, 0.f);
    if (k < INDIM) {
      int id; const float* tab; int kk; int wdt;
      if (k < 100)      { id = chars[lr * T_ + t];    tab = E_char;      kk = k;       wdt = 100; }
      else if (k < 200) { id = extchars[lr * T_ + t]; tab = E_extchar;   kk = k - 100; wdt = 100; }
      else if (k < 300) { id = bi[lr * T_ + t];       tab = E_bichar;    kk = k - 200; wdt = 100; }
      else if (k < 400) { id = ebi[lr * T_ + t];      tab = E_extbichar; kk = k - 300; wdt = 100; }
      else              { id = ctype[lr * T_ + t];    tab = E_ctype;     kk = k - 400; wdt = 20;  }
      v = *reinterpret_cast<const float4*>(tab + (size_t)id * wdt + kk);
    }
    *reinterpret_cast<float4*>(&feat[lr * 452 + k]) = v;
  }
  __syncthreads();

  int w = tid >> 6, l = tid & 63;
  int lrow = l & 15, lk8 = (l >> 4) << 3;
  f32x4v acc[8];
  #pragma unroll
  for (int i = 0; i < 8; ++i) acc[i] = (f32x4v){0.f, 0.f, 0.f, 0.f};

  for (int kt = 0; kt < 14; ++kt) {
    bfrag8 ah[2], al[2];
    #pragma unroll
    for (int mt = 0; mt < 2; ++mt) {
      const float* fp = &feat[(mt * 16 + lrow) * 452 + kt * 32 + lk8];
      float4 v0 = *reinterpret_cast<const float4*>(fp);
      float4 v1 = *reinterpret_cast<const float4*>(fp + 4);
      mk_hilo(v0, v1, ah[mt], al[mt]);
    }
    #pragma unroll
    for (int s = 0; s < 4; ++s) {
      int nt = w + (s << 2);
      if (nt < 13) {
        size_t fo = ((size_t)(nt * 14 + kt) * 64 + l) * 8;
        bfrag8 bh = *reinterpret_cast<const bfrag8*>(fcw_hi + fo);
        bfrag8 bl = *reinterpret_cast<const bfrag8*>(fcw_lo + fo);
        #pragma unroll
        for (int mt = 0; mt < 2; ++mt) {
          acc[s * 2 + mt] = __builtin_amdgcn_mfma_f32_16x16x32_bf16(ah[mt], bh, acc[s * 2 + mt], 0, 0, 0);
          acc[s * 2 + mt] = __builtin_amdgcn_mfma_f32_16x16x32_bf16(al[mt], bh, acc[s * 2 + mt], 0, 0, 0);
          acc[s * 2 + mt] = __builtin_amdgcn_mfma_f32_16x16x32_bf16(ah[mt], bl, acc[s * 2 + mt], 0, 0, 0);
        }
      }
    }
  }
  int r0 = rb * 32;
  #pragma unroll
  for (int s = 0; s < 4; ++s) {
    int nt = w + (s << 2);
    if (nt < 13) {
      int n = nt * 16 + lrow;
      if (n < LIN) {
        float bias = fc_b[n];
        #pragma unroll
        for (int mt = 0; mt < 2; ++mt) {
          #pragma unroll
          for (int rr = 0; rr < 4; ++rr) {
            int row = mt * 16 + ((l >> 4) << 2) + rr;
            x[(size_t)(r0 + row) * LIN + n] = tanhx(acc[s * 2 + mt][rr] + bias);
          }
        }
      }
    }
  }
}

// ---------------------------------------------------------------------------
// Kernel B: pre = x @ Wih'.T + b'  -> [2][8192][800] f32 (PERMUTED cols n').
// ---------------------------------------------------------------------------
__global__ __launch_bounds__(512) void xwih_kernel(
    const float* __restrict__ x, const unsigned short* __restrict__ wih_hi,
    const unsigned short* __restrict__ wih_lo, const float* __restrict__ b_l,
    const float* __restrict__ b_r, float* __restrict__ pre) {
  int bid = blockIdx.x;             // 640 = 2 * 64 * 5
  int dir = (bid >= 320) ? 1 : 0;
  int rem = bid - dir * 320;
  int rbm = rem / 5, nb = rem - rbm * 5;
  int m0 = rbm * 128, n0 = nb * 160;
  int tid = threadIdx.x, w = tid >> 6, l = tid & 63;
  int lrow = l & 15, lk8 = (l >> 4) << 3;
  const float* xd = x + (size_t)dir * 8192 * LIN;
  const unsigned short* wh = wih_hi + (size_t)dir * 179200;
  const unsigned short* wl = wih_lo + (size_t)dir * 179200;
  const float* bias = dir ? b_r : b_l;

  f32x4v acc[10];
  #pragma unroll
  for (int i = 0; i < 10; ++i) acc[i] = (f32x4v){0.f, 0.f, 0.f, 0.f};

  int row = m0 + w * 16 + lrow;
  for (int kt = 0; kt < 7; ++kt) {
    int kb = kt * 32 + lk8;
    bfrag8 ah = {0,0,0,0,0,0,0,0}, al = {0,0,0,0,0,0,0,0};
    if (kb <= 192) {
      const float* fp = xd + (size_t)row * LIN + kb;
      float4 v0 = *reinterpret_cast<const float4*>(fp);
      float4 v1 = *reinterpret_cast<const float4*>(fp + 4);
      mk_hilo(v0, v1, ah, al);
    }
    #pragma unroll
    for (int nt = 0; nt < 10; ++nt) {
      int ntg = nb * 10 + nt;
      size_t fo = ((size_t)(ntg * 7 + kt) * 64 + l) * 8;
      bfrag8 bh = *reinterpret_cast<const bfrag8*>(wh + fo);
      bfrag8 bl = *reinterpret_cast<const bfrag8*>(wl + fo);
      acc[nt] = __builtin_amdgcn_mfma_f32_16x16x32_bf16(ah, bh, acc[nt], 0, 0, 0);
      acc[nt] = __builtin_amdgcn_mfma_f32_16x16x32_bf16(al, bh, acc[nt], 0, 0, 0);
      acc[nt] = __builtin_amdgcn_mfma_f32_16x16x32_bf16(ah, bl, acc[nt], 0, 0, 0);
    }
  }
  #pragma unroll
  for (int nt = 0; nt < 10; ++nt) {
    int n = n0 + nt * 16 + lrow;                    // permuted col n'
    float bb = bias[(n & 3) * 200 + (n >> 2)];      // original bias row
    #pragma unroll
    for (int rr = 0; rr < 4; ++rr) {
      int r2 = m0 + w * 16 + ((l >> 4) << 2) + rr;
      pre[(size_t)dir * 8192 * G4 + (size_t)r2 * G4 + n] = acc[nt][rr] + bb;
    }
  }
}

// ---------------------------------------------------------------------------
// Kernel R: recurrence, 4 blocks = (dir, batch-half), 512 thr, M=16.
// gates^T = Whh' @ h^T; cell fully in-register. Per-step phase order:
//  A: issue next-step pre loads (double-buffered regs)   [loads FIRST in vm queue]
//  B: coalesced out-store of previous step's h (from LDS obuf, float4)
//  C: MFMA    D: cell (uses p loaded a step ago; ds_write h bf16 + f32)
//  E: lgkmcnt(0) + raw s_barrier (NO vmcnt drain — no memory-clobber asm)
// ---------------------------------------------------------------------------
__global__ __launch_bounds__(512, 2) void lstm_kernel(
    const float* __restrict__ pre, const float* __restrict__ Whh_l,
    const float* __restrict__ Whh_r, float* __restrict__ out) {
  __shared__ __align__(16) unsigned short hbufA[3584];   // [kt:7][lane:64][j:8] bf16
  __shared__ __align__(16) unsigned short hbufB[3584];
  __shared__ __align__(16) unsigned short whx[35840];    // tiles 40..49 A-frags
  __shared__ __align__(16) float obuf[2][3200];          // f32 h, [b:16][hcol:200]

  int bi = blockIdx.x;
  int dir = bi >> 1, half = bi & 1;
  const float* Whh = dir ? Whh_r : Whh_l;
  int tid = threadIdx.x, w = tid >> 6, l = tid & 63;
  int lrow = l & 15, lk8 = (l >> 4) << 3;

  // --- register-resident Whh' A-frags: tiles tau = w + 8i, i<5 ---
  bfrag8 Breg[5][7];
  #pragma unroll
  for (int i = 0; i < 5; ++i) {
    int np = (w + 8 * i) * 16 + lrow;
    int no = (np & 3) * 200 + (np >> 2);
    #pragma unroll
    for (int kt = 0; kt < 7; ++kt) {
      int kb = kt * 32 + lk8;
      bfrag8 bb = {0,0,0,0,0,0,0,0};
      if (kb <= 192) {
        const float* fp = Whh + (size_t)no * HD + kb;
        bb = mk_hi(*reinterpret_cast<const float4*>(fp),
                   *reinterpret_cast<const float4*>(fp + 4));
      }
      Breg[i][kt] = bb;
    }
  }
  // --- LDS tiles 40..49 ---
  for (int e = tid; e < 4480; e += 512) {
    int l2 = e & 63, f = e >> 6;          // f = tile*7 + kt
    int kt = f % 7, tile = f / 7;
    int np = (40 + tile) * 16 + (l2 & 15);
    int no = (np & 3) * 200 + (np >> 2);
    int kb = kt * 32 + ((l2 >> 4) << 3);
    bfrag8 bb = {0,0,0,0,0,0,0,0};
    if (kb <= 192) {
      const float* fp = Whh + (size_t)no * HD + kb;
      bb = mk_hi(*reinterpret_cast<const float4*>(fp),
                 *reinterpret_cast<const float4*>(fp + 4));
    }
    *reinterpret_cast<bfrag8*>(&whx[(size_t)e * 8]) = bb;
  }
  // zero h buffers (h0 = 0; K-pad positions stay zero forever)
  for (int e = tid; e < 896; e += 512) {
    reinterpret_cast<uint64_t*>(hbufA)[e] = 0;
    reinterpret_cast<uint64_t*>(hbufB)[e] = 0;
  }
  float c[7];
  #pragma unroll
  for (int i = 0; i < 7; ++i) c[i] = 0.f;

  // h-frag write slot (bf16, MFMA B layout)
  int hbase = 4 * w + (l >> 4);                       // hcol mod 32
  int hw = (lrow + 16 * ((hbase >> 3) & 3)) * 8 + (hbase & 7);
  // obuf cell slot (f32, [b][hcol])
  int ocell = lrow * 200 + 4 * w + (l >> 4);

  const float* psrc = pre + (size_t)dir * 8192 * G4
                    + (size_t)(dir ? 255 : 0) * 32 * G4
                    + (half * 16 + lrow) * G4 + ((l >> 4) << 2) + 16 * w;
  const int pstep = dir ? -(32 * G4) : (32 * G4);
  // coalesced out base: element (b, t, hcol) at obase + (b*256+t)*400 + hcol
  float* obase = out + (size_t)(half * 16) * 256 * 400 + dir * 200;

  __syncthreads();

  // prefetch pre for step 0 into pA
  float4 pA[7], pB[7];
  #pragma unroll
  for (int i = 0; i < 7; ++i)
    if (i < 6 || w < 2) pA[i] = *reinterpret_cast<const float4*>(psrc + 128 * i);
  psrc += pstep;

  auto STEP = [&](const unsigned short* rbuf, unsigned short* wbuf,
                  float4 (&pc)[7], float4 (&pn)[7], int it) {
    // --- A: issue next-step pre loads (first in vm queue) ---
    #pragma unroll
    for (int i = 0; i < 7; ++i)
      if (i < 6 || w < 2) pn[i] = *reinterpret_cast<const float4*>(psrc + 128 * i);
    psrc += pstep;
    // --- B: coalesced store of previous step's h ---
    if (it > 0) {
      int tprev = dir ? (256 - it) : (it - 1);
      const float* ob = (const float*)obuf[(it & 1) ^ 1];
      #pragma unroll
      for (int s = 0; s < 2; ++s) {
        int idx = tid + (s << 9);
        if (idx < 800) {
          int b = idx / 50, c4 = idx - b * 50;
          float4 v = *reinterpret_cast<const float4*>(ob + b * 200 + (c4 << 2));
          *reinterpret_cast<float4*>(obase + (size_t)(b * 256 + tprev) * 400 + (c4 << 2)) = v;
        }
      }
    }
    // --- C: MFMA phase ---
    f32x4v acc[7];
    #pragma unroll
    for (int i = 0; i < 7; ++i) acc[i] = (f32x4v){0.f, 0.f, 0.f, 0.f};
    #pragma unroll
    for (int kt = 0; kt < 7; ++kt) {
      bfrag8 hf = *reinterpret_cast<const bfrag8*>(&rbuf[kt * 512 + l * 8]);
      #pragma unroll
      for (int i = 0; i < 5; ++i)
        acc[i] = __builtin_amdgcn_mfma_f32_16x16x32_bf16(Breg[i][kt], hf, acc[i], 0, 0, 0);
      bfrag8 b5 = *reinterpret_cast<const bfrag8*>(&whx[(w * 7 + kt) * 512 + l * 8]);
      acc[5] = __builtin_amdgcn_mfma_f32_16x16x32_bf16(b5, hf, acc[5], 0, 0, 0);
      if (w < 2) {
        bfrag8 b6 = *reinterpret_cast<const bfrag8*>(&whx[((8 + w) * 7 + kt) * 512 + l * 8]);
        acc[6] = __builtin_amdgcn_mfma_f32_16x16x32_bf16(b6, hf, acc[6], 0, 0, 0);
      }
    }
    // --- D: cell (lane owns b=l&15, hcol=4*(w+8i)+(l>>4)) ---
    float* oc = (float*)obuf[it & 1] + ocell;
    #pragma unroll
    for (int i = 0; i < 7; ++i) {
      if (i < 6 || w < 2) {
        float ig = acc[i][0] + pc[i].x;
        float fg = acc[i][1] + pc[i].y;
        float gg = acc[i][2] + pc[i].z;
        float og = acc[i][3] + pc[i].w;
        float cv = sigm(fg) * c[i] + sigm(ig) * tanhx(gg);
        c[i] = cv;
        float h = sigm(og) * tanhx(cv);
        oc[32 * i] = h;
        wbuf[hw + i * 512] = f2bf(h);
      }
    }
    // --- E: barrier (lgkm only; vm queue stays in flight) ---
    __builtin_amdgcn_sched_barrier(0);
    asm volatile("s_waitcnt lgkmcnt(0)");
    __builtin_amdgcn_s_barrier();
    __builtin_amdgcn_sched_barrier(0);
  };

  for (int it = 0; it < 256; it += 2) {
    STEP(hbufA, hbufB, pA, pB, it);
    STEP(hbufB, hbufA, pB, pA, it + 1);
  }
  // final out store (t index 255 of this direction's traversal)
  {
    int tprev = dir ? 0 : 255;
    const float* ob = (const float*)obuf[1];
    #pragma unroll
    for (int s = 0; s < 2; ++s) {
      int idx = tid + (s << 9);
      if (idx < 800) {
        int b = idx / 50, c4 = idx - b * 50;
        float4 v = *reinterpret_cast<const float4*>(ob + b * 200 + (c4 << 2));
        *reinterpret_cast<float4*>(obase + (size_t)(b * 256 + tprev) * 400 + (c4 << 2)) = v;
      }
    }
  }
}

// ---------------------------------------------------------------------------
extern "C" void kernel_launch(void* const* d_in, const int* in_sizes, int n_in,
                              void* d_out, int out_size, void* d_ws, size_t ws_size,
                              hipStream_t stream) {
  (void)in_sizes; (void)n_in; (void)out_size; (void)ws_size;
  const int* chars        = (const int*)d_in[0];
  const int* left_bichar  = (const int*)d_in[1];
  const int* right_bichar = (const int*)d_in[2];
  const int* extchars     = (const int*)d_in[3];
  const int* extleft      = (const int*)d_in[4];
  const int* extright     = (const int*)d_in[5];
  const int* ctype        = (const int*)d_in[6];
  const float* E_char      = (const float*)d_in[7];
  const float* E_extchar   = (const float*)d_in[8];
  const float* E_bichar    = (const float*)d_in[9];
  const float* E_extbichar = (const float*)d_in[10];
  const float* E_ctype     = (const float*)d_in[11];
  const float* fc_w  = (const float*)d_in[12];
  const float* fc_b  = (const float*)d_in[13];
  const float* Wih_l = (const float*)d_in[14];
  const float* Whh_l = (const float*)d_in[15];
  const float* b_l   = (const float*)d_in[16];
  const float* Wih_r = (const float*)d_in[17];
  const float* Whh_r = (const float*)d_in[18];
  const float* b_r   = (const float*)d_in[19];
  float* out = (float*)d_out;
  char* ws = (char*)d_ws;

  float* x   = (float*)(ws);                        // 13,107,200 B
  float* pre = (float*)(ws + 13107200);             // 52,428,800 B
  unsigned short* fcw_hi = (unsigned short*)(ws + 65536000);   // 186,368
  unsigned short* fcw_lo = (unsigned short*)(ws + 65722368);   // 186,368
  unsigned short* wih_hi = (unsigned short*)(ws + 65908736);   // 716,800
  unsigned short* wih_lo = (unsigned short*)(ws + 66625536);   // 716,800

  presplit_kernel<<<256, 256, 0, stream>>>(fc_w, Wih_l, Wih_r, fcw_hi, fcw_lo, wih_hi, wih_lo);
  fc_kernel<<<512, 256, 0, stream>>>(chars, left_bichar, right_bichar, extchars,
                                     extleft, extright, ctype, E_char, E_extchar,
                                     E_bichar, E_extbichar, E_ctype, fc_b,
                                     fcw_hi, fcw_lo, x);
  xwih_kernel<<<640, 512, 0, stream>>>(x, wih_hi, wih_lo, b_l, b_r, pre);
  lstm_kernel<<<4, 512, 0, stream>>>(pre, Whh_l, Whh_r, out);
}

// Round 4
// 761.496 us; speedup vs baseline: 1.5423x; 1.5423x over previous
//
#include <hip/hip_runtime.h>
#include <stdint.h>

// Problem constants
#define B_    32
#define T_    256
#define CD    100
#define BD    100
#define TD    20
#define LIN   200
#define HD    200
#define INDIM 420
#define G4    800   // 4*H

typedef __attribute__((ext_vector_type(8))) short bfrag8;   // 8 bf16 (4 VGPRs)
typedef __attribute__((ext_vector_type(4))) float f32x4v;   // MFMA accumulator

static __device__ __forceinline__ unsigned short f2bf(float f) {
  unsigned u = __float_as_uint(f);
  u = u + 0x7fffu + ((u >> 16) & 1u);   // RTNE
  return (unsigned short)(u >> 16);
}
static __device__ __forceinline__ float bf2f(unsigned short s) {
  return __uint_as_float(((unsigned)s) << 16);
}
static __device__ __forceinline__ float sigm(float x) {
  return __builtin_amdgcn_rcpf(1.0f + __builtin_amdgcn_exp2f(x * -1.4426950408889634f));
}
static __device__ __forceinline__ float tanhx(float x) {
  return 1.0f - 2.0f * __builtin_amdgcn_rcpf(1.0f + __builtin_amdgcn_exp2f(x * 2.8853900817779268f));
}

static __device__ __forceinline__ void mk_hilo(float4 a, float4 b, bfrag8& hi, bfrag8& lo) {
  float q[8] = {a.x, a.y, a.z, a.w, b.x, b.y, b.z, b.w};
  #pragma unroll
  for (int j = 0; j < 8; ++j) {
    unsigned short h = f2bf(q[j]);
    hi[j] = (short)h;
    lo[j] = (short)f2bf(q[j] - bf2f(h));
  }
}
static __device__ __forceinline__ bfrag8 mk_hi(float4 a, float4 b) {
  bfrag8 r;
  float q[8] = {a.x, a.y, a.z, a.w, b.x, b.y, b.z, b.w};
  #pragma unroll
  for (int j = 0; j < 8; ++j) r[j] = (short)f2bf(q[j]);
  return r;
}

// ---------------------------------------------------------------------------
// Kernel W: pre-split fc_w and Wih_{l,r} into hi/lo bf16 in MFMA fragment layout
// frag layout: elem i = ((nt*KT + kt)*64 + lane)*8 + j ;
//   n = nt*16 + (lane&15), k = kt*32 + (lane>>4)*8 + j
// Wih rows are PERMUTED: frag col n' maps to original row (n'&3)*200 + (n'>>2)
// ---------------------------------------------------------------------------
__global__ void presplit_kernel(const float* __restrict__ fc_w,
                                const float* __restrict__ Wih_l,
                                const float* __restrict__ Wih_r,
                                unsigned short* __restrict__ fcw_hi,
                                unsigned short* __restrict__ fcw_lo,
                                unsigned short* __restrict__ wih_hi,
                                unsigned short* __restrict__ wih_lo) {
  int tid = blockIdx.x * blockDim.x + threadIdx.x;
  int stride = gridDim.x * blockDim.x;
  for (int i = tid; i < 13 * 14 * 512; i += stride) {
    int j = i & 7, l = (i >> 3) & 63, f = i >> 9;
    int kt = f % 14, nt = f / 14;
    int n = nt * 16 + (l & 15);
    int k = kt * 32 + ((l >> 4) << 3) + j;
    float v = (n < LIN && k < INDIM) ? fc_w[n * INDIM + k] : 0.0f;
    unsigned short h = f2bf(v);
    fcw_hi[i] = h;
    fcw_lo[i] = f2bf(v - bf2f(h));
  }
  for (int d = 0; d < 2; ++d) {
    const float* W = d ? Wih_r : Wih_l;
    unsigned short* oh = wih_hi + (size_t)d * 179200;
    unsigned short* ol = wih_lo + (size_t)d * 179200;
    for (int i = tid; i < 50 * 7 * 512; i += stride) {
      int j = i & 7, l = (i >> 3) & 63, f = i >> 9;
      int kt = f % 7, nt = f / 7;
      int np = nt * 16 + (l & 15);                 // permuted col n'
      int no = (np & 3) * 200 + (np >> 2);         // original Wih row
      int k = kt * 32 + ((l >> 4) << 3) + j;
      float v = (k < LIN) ? W[no * LIN + k] : 0.0f;
      unsigned short h = f2bf(v);
      oh[i] = h;
      ol[i] = f2bf(v - bf2f(h));
    }
  }
}

// ---------------------------------------------------------------------------
// Kernel A: embedding gather + concat(420) + FC + tanh -> x [2*8192][200] f32
// ---------------------------------------------------------------------------
__global__ __launch_bounds__(256) void fc_kernel(
    const int* __restrict__ chars, const int* __restrict__ left_bichar,
    const int* __restrict__ right_bichar, const int* __restrict__ extchars,
    const int* __restrict__ extleft, const int* __restrict__ extright,
    const int* __restrict__ ctype,
    const float* __restrict__ E_char, const float* __restrict__ E_extchar,
    const float* __restrict__ E_bichar, const float* __restrict__ E_extbichar,
    const float* __restrict__ E_ctype, const float* __restrict__ fc_b,
    const unsigned short* __restrict__ fcw_hi, const unsigned short* __restrict__ fcw_lo,
    float* __restrict__ x) {
  __shared__ __align__(16) float feat[32 * 452];
  int rb = blockIdx.x;            // dir*256 + t
  int dir = rb >> 8;
  int t = rb & 255;
  int tid = threadIdx.x;
  const int* bi  = dir ? right_bichar : left_bichar;
  const int* ebi = dir ? extright : extleft;

  for (int cc = tid; cc < 32 * 113; cc += 256) {
    int lr = cc / 113, kc = cc - lr * 113;
    int k = kc << 2;
    float4 v = make_float4(0.f, 0.f, 0.f, 0.f);
    if (k < INDIM) {
      int id; const float* tab; int kk; int wdt;
      if (k < 100)      { id = chars[lr * T_ + t];    tab = E_char;      kk = k;       wdt = 100; }
      else if (k < 200) { id = extchars[lr * T_ + t]; tab = E_extchar;   kk = k - 100; wdt = 100; }
      else if (k < 300) { id = bi[lr * T_ + t];       tab = E_bichar;    kk = k - 200; wdt = 100; }
      else if (k < 400) { id = ebi[lr * T_ + t];      tab = E_extbichar; kk = k - 300; wdt = 100; }
      else              { id = ctype[lr * T_ + t];    tab = E_ctype;     kk = k - 400; wdt = 20;  }
      v = *reinterpret_cast<const float4*>(tab + (size_t)id * wdt + kk);
    }
    *reinterpret_cast<float4*>(&feat[lr * 452 + k]) = v;
  }
  __syncthreads();

  int w = tid >> 6, l = tid & 63;
  int lrow = l & 15, lk8 = (l >> 4) << 3;
  f32x4v acc[8];
  #pragma unroll
  for (int i = 0; i < 8; ++i) acc[i] = (f32x4v){0.f, 0.f, 0.f, 0.f};

  for (int kt = 0; kt < 14; ++kt) {
    bfrag8 ah[2], al[2];
    #pragma unroll
    for (int mt = 0; mt < 2; ++mt) {
      const float* fp = &feat[(mt * 16 + lrow) * 452 + kt * 32 + lk8];
      float4 v0 = *reinterpret_cast<const float4*>(fp);
      float4 v1 = *reinterpret_cast<const float4*>(fp + 4);
      mk_hilo(v0, v1, ah[mt], al[mt]);
    }
    #pragma unroll
    for (int s = 0; s < 4; ++s) {
      int nt = w + (s << 2);
      if (nt < 13) {
        size_t fo = ((size_t)(nt * 14 + kt) * 64 + l) * 8;
        bfrag8 bh = *reinterpret_cast<const bfrag8*>(fcw_hi + fo);
        bfrag8 bl = *reinterpret_cast<const bfrag8*>(fcw_lo + fo);
        #pragma unroll
        for (int mt = 0; mt < 2; ++mt) {
          acc[s * 2 + mt] = __builtin_amdgcn_mfma_f32_16x16x32_bf16(ah[mt], bh, acc[s * 2 + mt], 0, 0, 0);
          acc[s * 2 + mt] = __builtin_amdgcn_mfma_f32_16x16x32_bf16(al[mt], bh, acc[s * 2 + mt], 0, 0, 0);
          acc[s * 2 + mt] = __builtin_amdgcn_mfma_f32_16x16x32_bf16(ah[mt], bl, acc[s * 2 + mt], 0, 0, 0);
        }
      }
    }
  }
  int r0 = rb * 32;
  #pragma unroll
  for (int s = 0; s < 4; ++s) {
    int nt = w + (s << 2);
    if (nt < 13) {
      int n = nt * 16 + lrow;
      if (n < LIN) {
        float bias = fc_b[n];
        #pragma unroll
        for (int mt = 0; mt < 2; ++mt) {
          #pragma unroll
          for (int rr = 0; rr < 4; ++rr) {
            int row = mt * 16 + ((l >> 4) << 2) + rr;
            x[(size_t)(r0 + row) * LIN + n] = tanhx(acc[s * 2 + mt][rr] + bias);
          }
        }
      }
    }
  }
}

// ---------------------------------------------------------------------------
// Kernel B: pre = x @ Wih'.T + b'  (PERMUTED cols n'), written in the lstm
// kernel's exact wave/lane step order:
//   pre[(((dh*256 + t)*50 + chunk)*64 + lane)*4 + g]
//   dh = dir*2 + half; chunk = i*8+w (i<6) or 48+w (i==6, w<2);
//   lane = b + 16*lhi;  cell: b, hcol = 32i + 4w + lhi; g = gate.
// -> each lstm step reads ONE contiguous 51.2 KB block, 1KB per wave-instr.
// ---------------------------------------------------------------------------
__global__ __launch_bounds__(512) void xwih_kernel(
    const float* __restrict__ x, const unsigned short* __restrict__ wih_hi,
    const unsigned short* __restrict__ wih_lo, const float* __restrict__ b_l,
    const float* __restrict__ b_r, float* __restrict__ pre) {
  int bid = blockIdx.x;             // 640 = 2 * 64 * 5
  int dir = (bid >= 320) ? 1 : 0;
  int rem = bid - dir * 320;
  int rbm = rem / 5, nb = rem - rbm * 5;
  int m0 = rbm * 128, n0 = nb * 160;
  int tid = threadIdx.x, w = tid >> 6, l = tid & 63;
  int lrow = l & 15, lk8 = (l >> 4) << 3;
  const float* xd = x + (size_t)dir * 8192 * LIN;
  const unsigned short* wh = wih_hi + (size_t)dir * 179200;
  const unsigned short* wl = wih_lo + (size_t)dir * 179200;
  const float* bias = dir ? b_r : b_l;

  f32x4v acc[10];
  #pragma unroll
  for (int i = 0; i < 10; ++i) acc[i] = (f32x4v){0.f, 0.f, 0.f, 0.f};

  int row = m0 + w * 16 + lrow;
  for (int kt = 0; kt < 7; ++kt) {
    int kb = kt * 32 + lk8;
    bfrag8 ah = {0,0,0,0,0,0,0,0}, al = {0,0,0,0,0,0,0,0};
    if (kb <= 192) {
      const float* fp = xd + (size_t)row * LIN + kb;
      float4 v0 = *reinterpret_cast<const float4*>(fp);
      float4 v1 = *reinterpret_cast<const float4*>(fp + 4);
      mk_hilo(v0, v1, ah, al);
    }
    #pragma unroll
    for (int nt = 0; nt < 10; ++nt) {
      int ntg = nb * 10 + nt;
      size_t fo = ((size_t)(ntg * 7 + kt) * 64 + l) * 8;
      bfrag8 bh = *reinterpret_cast<const bfrag8*>(wh + fo);
      bfrag8 bl = *reinterpret_cast<const bfrag8*>(wl + fo);
      acc[nt] = __builtin_amdgcn_mfma_f32_16x16x32_bf16(ah, bh, acc[nt], 0, 0, 0);
      acc[nt] = __builtin_amdgcn_mfma_f32_16x16x32_bf16(al, bh, acc[nt], 0, 0, 0);
      acc[nt] = __builtin_amdgcn_mfma_f32_16x16x32_bf16(ah, bl, acc[nt], 0, 0, 0);
    }
  }
  #pragma unroll
  for (int nt = 0; nt < 10; ++nt) {
    int n = n0 + nt * 16 + lrow;                    // permuted col n'
    float bb = bias[(n & 3) * 200 + (n >> 2)];      // original bias row
    int hcol = n >> 2, g = n & 3;
    int i6 = hcol >> 5;                             // 0..6
    int hc5 = hcol & 31;
    int wv = hc5 >> 2, lhi = hc5 & 3;
    int chunk = (i6 < 6) ? (i6 * 8 + wv) : (48 + wv);
    #pragma unroll
    for (int rr = 0; rr < 4; ++rr) {
      int r2 = m0 + w * 16 + ((l >> 4) << 2) + rr;  // global row = t*32 + b32
      int t = r2 >> 5, b32 = r2 & 31;
      int hf2 = b32 >> 4, b = b32 & 15;
      int lane = b + 16 * lhi;
      size_t dst = ((((size_t)(dir * 2 + hf2) * 256 + t) * 50 + chunk) * 64 + lane) * 4 + g;
      pre[dst] = acc[nt][rr] + bb;
    }
  }
}

// ---------------------------------------------------------------------------
// Kernel R: recurrence, 4 blocks = (dir, batch-half), 512 thr, M=16.
// gates^T = Whh' @ h^T; cell fully in-register. Per step:
//  A: issue next-step pre loads (contiguous 51.2KB block, dbuf regs)
//  C: MFMA   D: cell + direct out stores + ds_write h(bf16)
//  E: sched_barrier(0xF) | lgkmcnt(0) | s_barrier | sched_barrier(0xF)
//     (memory pinned; ALU/VALU/MFMA free to cross — compiler may pipeline)
// ---------------------------------------------------------------------------
__global__ __launch_bounds__(512, 2) void lstm_kernel(
    const float* __restrict__ pre, const float* __restrict__ Whh_l,
    const float* __restrict__ Whh_r, float* __restrict__ out) {
  __shared__ __align__(16) unsigned short hbufA[3584];   // [kt:7][lane:64][j:8] bf16
  __shared__ __align__(16) unsigned short hbufB[3584];
  __shared__ __align__(16) unsigned short whx[35840];    // tiles 40..49 A-frags

  int bi = blockIdx.x;
  int dir = bi >> 1, half = bi & 1;
  const float* Whh = dir ? Whh_r : Whh_l;
  int tid = threadIdx.x, w = tid >> 6, l = tid & 63;
  int lrow = l & 15, lk8 = (l >> 4) << 3;

  // --- register-resident Whh' A-frags: tiles tau = w + 8i, i<5 ---
  bfrag8 Breg[5][7];
  #pragma unroll
  for (int i = 0; i < 5; ++i) {
    int np = (w + 8 * i) * 16 + lrow;
    int no = (np & 3) * 200 + (np >> 2);
    #pragma unroll
    for (int kt = 0; kt < 7; ++kt) {
      int kb = kt * 32 + lk8;
      bfrag8 bb = {0,0,0,0,0,0,0,0};
      if (kb <= 192) {
        const float* fp = Whh + (size_t)no * HD + kb;
        bb = mk_hi(*reinterpret_cast<const float4*>(fp),
                   *reinterpret_cast<const float4*>(fp + 4));
      }
      Breg[i][kt] = bb;
    }
  }
  // --- LDS tiles 40..49 ---
  for (int e = tid; e < 4480; e += 512) {
    int l2 = e & 63, f = e >> 6;          // f = tile*7 + kt
    int kt = f % 7, tile = f / 7;
    int np = (40 + tile) * 16 + (l2 & 15);
    int no = (np & 3) * 200 + (np >> 2);
    int kb = kt * 32 + ((l2 >> 4) << 3);
    bfrag8 bb = {0,0,0,0,0,0,0,0};
    if (kb <= 192) {
      const float* fp = Whh + (size_t)no * HD + kb;
      bb = mk_hi(*reinterpret_cast<const float4*>(fp),
                 *reinterpret_cast<const float4*>(fp + 4));
    }
    *reinterpret_cast<bfrag8*>(&whx[(size_t)e * 8]) = bb;
  }
  // zero h buffers (h0 = 0; K-pad positions stay zero forever)
  for (int e = tid; e < 896; e += 512) {
    reinterpret_cast<uint64_t*>(hbufA)[e] = 0;
    reinterpret_cast<uint64_t*>(hbufB)[e] = 0;
  }
  float c[7];
  #pragma unroll
  for (int i = 0; i < 7; ++i) c[i] = 0.f;

  // h-frag write slot (bf16, MFMA B layout); kt handled by +i*512
  int hbase = 4 * w + (l >> 4);                       // hcol mod 32
  int hw = (lrow + 16 * ((hbase >> 3) & 3)) * 8 + (hbase & 7);

  // pre: contiguous per (dh, t); per-lane base covers chunks w+8i and 48+w
  const float* psrcL = pre + ((size_t)(dir * 2 + half) * 256 + (dir ? 255 : 0)) * 12800
                     + w * 256 + (l << 2);
  const int pstep = dir ? -12800 : 12800;
  float* outp = out + (size_t)((half * 16 + lrow) * 256 + (dir ? 255 : 0)) * 400
              + dir * 200 + (l >> 4) + 4 * w;
  const int ostep = dir ? -400 : 400;

  __syncthreads();

  // prefetch pre for step 0 into pA
  float4 pA[7], pB[7];
  #pragma unroll
  for (int i = 0; i < 6; ++i) pA[i] = *reinterpret_cast<const float4*>(psrcL + i * 2048);
  if (w < 2) pA[6] = *reinterpret_cast<const float4*>(psrcL + 12288);
  psrcL += pstep;

  auto STEP = [&](const unsigned short* rbuf, unsigned short* wbuf,
                  float4 (&pc)[7], float4 (&pn)[7]) {
    // --- A: issue next-step pre loads (contiguous block; first in vm queue) ---
    #pragma unroll
    for (int i = 0; i < 6; ++i) pn[i] = *reinterpret_cast<const float4*>(psrcL + i * 2048);
    if (w < 2) pn[6] = *reinterpret_cast<const float4*>(psrcL + 12288);
    psrcL += pstep;
    // --- C: MFMA phase ---
    f32x4v acc[7];
    #pragma unroll
    for (int i = 0; i < 7; ++i) acc[i] = (f32x4v){0.f, 0.f, 0.f, 0.f};
    #pragma unroll
    for (int kt = 0; kt < 7; ++kt) {
      bfrag8 hf = *reinterpret_cast<const bfrag8*>(&rbuf[kt * 512 + l * 8]);
      #pragma unroll
      for (int i = 0; i < 5; ++i)
        acc[i] = __builtin_amdgcn_mfma_f32_16x16x32_bf16(Breg[i][kt], hf, acc[i], 0, 0, 0);
      bfrag8 b5 = *reinterpret_cast<const bfrag8*>(&whx[(w * 7 + kt) * 512 + l * 8]);
      acc[5] = __builtin_amdgcn_mfma_f32_16x16x32_bf16(b5, hf, acc[5], 0, 0, 0);
      if (w < 2) {
        bfrag8 b6 = *reinterpret_cast<const bfrag8*>(&whx[((8 + w) * 7 + kt) * 512 + l * 8]);
        acc[6] = __builtin_amdgcn_mfma_f32_16x16x32_bf16(b6, hf, acc[6], 0, 0, 0);
      }
    }
    // --- D: cell (lane owns b=l&15, hcol=4w+(l>>4)+32i) + direct stores ---
    #pragma unroll
    for (int i = 0; i < 7; ++i) {
      if (i < 6 || w < 2) {
        float ig = acc[i][0] + pc[i].x;
        float fg = acc[i][1] + pc[i].y;
        float gg = acc[i][2] + pc[i].z;
        float og = acc[i][3] + pc[i].w;
        float cv = sigm(fg) * c[i] + sigm(ig) * tanhx(gg);
        c[i] = cv;
        float h = sigm(og) * tanhx(cv);
        outp[32 * i] = h;
        wbuf[hw + i * 512] = f2bf(h);
      }
    }
    outp += ostep;
    // --- E: barrier; memory pinned, reg-only ops may cross ---
    __builtin_amdgcn_sched_barrier(0x1 | 0x2 | 0x4 | 0x8);
    asm volatile("s_waitcnt lgkmcnt(0)");
    __builtin_amdgcn_s_barrier();
    __builtin_amdgcn_sched_barrier(0x1 | 0x2 | 0x4 | 0x8);
  };

  for (int it = 0; it < 128; ++it) {
    STEP(hbufA, hbufB, pA, pB);
    STEP(hbufB, hbufA, pB, pA);
  }
}

// ---------------------------------------------------------------------------
extern "C" void kernel_launch(void* const* d_in, const int* in_sizes, int n_in,
                              void* d_out, int out_size, void* d_ws, size_t ws_size,
                              hipStream_t stream) {
  (void)in_sizes; (void)n_in; (void)out_size; (void)ws_size;
  const int* chars        = (const int*)d_in[0];
  const int* left_bichar  = (const int*)d_in[1];
  const int* right_bichar = (const int*)d_in[2];
  const int* extchars     = (const int*)d_in[3];
  const int* extleft      = (const int*)d_in[4];
  const int* extright     = (const int*)d_in[5];
  const int* ctype        = (const int*)d_in[6];
  const float* E_char      = (const float*)d_in[7];
  const float* E_extchar   = (const float*)d_in[8];
  const float* E_bichar    = (const float*)d_in[9];
  const float* E_extbichar = (const float*)d_in[10];
  const float* E_ctype     = (const float*)d_in[11];
  const float* fc_w  = (const float*)d_in[12];
  const float* fc_b  = (const float*)d_in[13];
  const float* Wih_l = (const float*)d_in[14];
  const float* Whh_l = (const float*)d_in[15];
  const float* b_l   = (const float*)d_in[16];
  const float* Wih_r = (const float*)d_in[17];
  const float* Whh_r = (const float*)d_in[18];
  const float* b_r   = (const float*)d_in[19];
  float* out = (float*)d_out;
  char* ws = (char*)d_ws;

  float* x   = (float*)(ws);                        // 13,107,200 B
  float* pre = (float*)(ws + 13107200);             // 52,428,800 B
  unsigned short* fcw_hi = (unsigned short*)(ws + 65536000);   // 186,368
  unsigned short* fcw_lo = (unsigned short*)(ws + 65722368);   // 186,368
  unsigned short* wih_hi = (unsigned short*)(ws + 65908736);   // 716,800
  unsigned short* wih_lo = (unsigned short*)(ws + 66625536);   // 716,800

  presplit_kernel<<<256, 256, 0, stream>>>(fc_w, Wih_l, Wih_r, fcw_hi, fcw_lo, wih_hi, wih_lo);
  fc_kernel<<<512, 256, 0, stream>>>(chars, left_bichar, right_bichar, extchars,
                                     extleft, extright, ctype, E_char, E_extchar,
                                     E_bichar, E_extbichar, E_ctype, fc_b,
                                     fcw_hi, fcw_lo, x);
  xwih_kernel<<<640, 512, 0, stream>>>(x, wih_hi, wih_lo, b_l, b_r, pre);
  lstm_kernel<<<4, 512, 0, stream>>>(pre, Whh_l, Whh_r, out);
}

// Round 5
// 738.375 us; speedup vs baseline: 1.5906x; 1.0313x over previous
//
#include <hip/hip_runtime.h>
#include <stdint.h>

// Problem constants
#define B_    32
#define T_    256
#define CD    100
#define BD    100
#define TD    20
#define LIN   200
#define HD    200
#define INDIM 420
#define G4    800   // 4*H

typedef __attribute__((ext_vector_type(8))) short bfrag8;   // 8 bf16 (4 VGPRs)
typedef __attribute__((ext_vector_type(4))) float f32x4v;   // MFMA accumulator

static __device__ __forceinline__ unsigned short f2bf(float f) {
  unsigned u = __float_as_uint(f);
  u = u + 0x7fffu + ((u >> 16) & 1u);   // RTNE
  return (unsigned short)(u >> 16);
}
static __device__ __forceinline__ float bf2f(unsigned short s) {
  return __uint_as_float(((unsigned)s) << 16);
}
static __device__ __forceinline__ float sigm(float x) {
  return __builtin_amdgcn_rcpf(1.0f + __builtin_amdgcn_exp2f(x * -1.4426950408889634f));
}
static __device__ __forceinline__ float tanhx(float x) {
  return 1.0f - 2.0f * __builtin_amdgcn_rcpf(1.0f + __builtin_amdgcn_exp2f(x * 2.8853900817779268f));
}
static __device__ __forceinline__ float clamp40(float x) {
  return fminf(fmaxf(x, -40.0f), 40.0f);
}

static __device__ __forceinline__ void mk_hilo(float4 a, float4 b, bfrag8& hi, bfrag8& lo) {
  float q[8] = {a.x, a.y, a.z, a.w, b.x, b.y, b.z, b.w};
  #pragma unroll
  for (int j = 0; j < 8; ++j) {
    unsigned short h = f2bf(q[j]);
    hi[j] = (short)h;
    lo[j] = (short)f2bf(q[j] - bf2f(h));
  }
}
static __device__ __forceinline__ bfrag8 mk_hi(float4 a, float4 b) {
  bfrag8 r;
  float q[8] = {a.x, a.y, a.z, a.w, b.x, b.y, b.z, b.w};
  #pragma unroll
  for (int j = 0; j < 8; ++j) r[j] = (short)f2bf(q[j]);
  return r;
}

// ---------------------------------------------------------------------------
// Kernel W: pre-split fc_w and Wih_{l,r} into hi/lo bf16 in MFMA fragment layout
// frag layout: elem i = ((nt*KT + kt)*64 + lane)*8 + j ;
//   n = nt*16 + (lane&15), k = kt*32 + (lane>>4)*8 + j
// Wih rows are PERMUTED: frag col n' maps to original row (n'&3)*200 + (n'>>2)
// ---------------------------------------------------------------------------
__global__ void presplit_kernel(const float* __restrict__ fc_w,
                                const float* __restrict__ Wih_l,
                                const float* __restrict__ Wih_r,
                                unsigned short* __restrict__ fcw_hi,
                                unsigned short* __restrict__ fcw_lo,
                                unsigned short* __restrict__ wih_hi,
                                unsigned short* __restrict__ wih_lo) {
  int tid = blockIdx.x * blockDim.x + threadIdx.x;
  int stride = gridDim.x * blockDim.x;
  for (int i = tid; i < 13 * 14 * 512; i += stride) {
    int j = i & 7, l = (i >> 3) & 63, f = i >> 9;
    int kt = f % 14, nt = f / 14;
    int n = nt * 16 + (l & 15);
    int k = kt * 32 + ((l >> 4) << 3) + j;
    float v = (n < LIN && k < INDIM) ? fc_w[n * INDIM + k] : 0.0f;
    unsigned short h = f2bf(v);
    fcw_hi[i] = h;
    fcw_lo[i] = f2bf(v - bf2f(h));
  }
  for (int d = 0; d < 2; ++d) {
    const float* W = d ? Wih_r : Wih_l;
    unsigned short* oh = wih_hi + (size_t)d * 179200;
    unsigned short* ol = wih_lo + (size_t)d * 179200;
    for (int i = tid; i < 50 * 7 * 512; i += stride) {
      int j = i & 7, l = (i >> 3) & 63, f = i >> 9;
      int kt = f % 7, nt = f / 7;
      int np = nt * 16 + (l & 15);                 // permuted col n'
      int no = (np & 3) * 200 + (np >> 2);         // original Wih row
      int k = kt * 32 + ((l >> 4) << 3) + j;
      float v = (k < LIN) ? W[no * LIN + k] : 0.0f;
      unsigned short h = f2bf(v);
      oh[i] = h;
      ol[i] = f2bf(v - bf2f(h));
    }
  }
}

// ---------------------------------------------------------------------------
// Kernel A: embedding gather + concat(420) + FC + tanh -> x [2*8192][200] f32
// ---------------------------------------------------------------------------
__global__ __launch_bounds__(256) void fc_kernel(
    const int* __restrict__ chars, const int* __restrict__ left_bichar,
    const int* __restrict__ right_bichar, const int* __restrict__ extchars,
    const int* __restrict__ extleft, const int* __restrict__ extright,
    const int* __restrict__ ctype,
    const float* __restrict__ E_char, const float* __restrict__ E_extchar,
    const float* __restrict__ E_bichar, const float* __restrict__ E_extbichar,
    const float* __restrict__ E_ctype, const float* __restrict__ fc_b,
    const unsigned short* __restrict__ fcw_hi, const unsigned short* __restrict__ fcw_lo,
    float* __restrict__ x) {
  __shared__ __align__(16) float feat[32 * 452];
  int rb = blockIdx.x;            // dir*256 + t
  int dir = rb >> 8;
  int t = rb & 255;
  int tid = threadIdx.x;
  const int* bi  = dir ? right_bichar : left_bichar;
  const int* ebi = dir ? extright : extleft;

  for (int cc = tid; cc < 32 * 113; cc += 256) {
    int lr = cc / 113, kc = cc - lr * 113;
    int k = kc << 2;
    float4 v = make_float4(0.f, 0.f, 0.f, 0.f);
    if (k < INDIM) {
      int id; const float* tab; int kk; int wdt;
      if (k < 100)      { id = chars[lr * T_ + t];    tab = E_char;      kk = k;       wdt = 100; }
      else if (k < 200) { id = extchars[lr * T_ + t]; tab = E_extchar;   kk = k - 100; wdt = 100; }
      else if (k < 300) { id = bi[lr * T_ + t];       tab = E_bichar;    kk = k - 200; wdt = 100; }
      else if (k < 400) { id = ebi[lr * T_ + t];      tab = E_extbichar; kk = k - 300; wdt = 100; }
      else              { id = ctype[lr * T_ + t];    tab = E_ctype;     kk = k - 400; wdt = 20;  }
      v = *reinterpret_cast<const float4*>(tab + (size_t)id * wdt + kk);
    }
    *reinterpret_cast<float4*>(&feat[lr * 452 + k]) = v;
  }
  __syncthreads();

  int w = tid >> 6, l = tid & 63;
  int lrow = l & 15, lk8 = (l >> 4) << 3;
  f32x4v acc[8];
  #pragma unroll
  for (int i = 0; i < 8; ++i) acc[i] = (f32x4v){0.f, 0.f, 0.f, 0.f};

  for (int kt = 0; kt < 14; ++kt) {
    bfrag8 ah[2], al[2];
    #pragma unroll
    for (int mt = 0; mt < 2; ++mt) {
      const float* fp = &feat[(mt * 16 + lrow) * 452 + kt * 32 + lk8];
      float4 v0 = *reinterpret_cast<const float4*>(fp);
      float4 v1 = *reinterpret_cast<const float4*>(fp + 4);
      mk_hilo(v0, v1, ah[mt], al[mt]);
    }
    #pragma unroll
    for (int s = 0; s < 4; ++s) {
      int nt = w + (s << 2);
      if (nt < 13) {
        size_t fo = ((size_t)(nt * 14 + kt) * 64 + l) * 8;
        bfrag8 bh = *reinterpret_cast<const bfrag8*>(fcw_hi + fo);
        bfrag8 bl = *reinterpret_cast<const bfrag8*>(fcw_lo + fo);
        #pragma unroll
        for (int mt = 0; mt < 2; ++mt) {
          acc[s * 2 + mt] = __builtin_amdgcn_mfma_f32_16x16x32_bf16(ah[mt], bh, acc[s * 2 + mt], 0, 0, 0);
          acc[s * 2 + mt] = __builtin_amdgcn_mfma_f32_16x16x32_bf16(al[mt], bh, acc[s * 2 + mt], 0, 0, 0);
          acc[s * 2 + mt] = __builtin_amdgcn_mfma_f32_16x16x32_bf16(ah[mt], bl, acc[s * 2 + mt], 0, 0, 0);
        }
      }
    }
  }
  int r0 = rb * 32;
  #pragma unroll
  for (int s = 0; s < 4; ++s) {
    int nt = w + (s << 2);
    if (nt < 13) {
      int n = nt * 16 + lrow;
      if (n < LIN) {
        float bias = fc_b[n];
        #pragma unroll
        for (int mt = 0; mt < 2; ++mt) {
          #pragma unroll
          for (int rr = 0; rr < 4; ++rr) {
            int row = mt * 16 + ((l >> 4) << 2) + rr;
            x[(size_t)(r0 + row) * LIN + n] = tanhx(acc[s * 2 + mt][rr] + bias);
          }
        }
      }
    }
  }
}

// ---------------------------------------------------------------------------
// Kernel B: pre = x @ Wih'.T + b'  (PERMUTED cols n'), written in the lstm
// kernel's exact wave/lane step order:
//   pre[(((dh*256 + t)*50 + chunk)*64 + lane)*4 + g]
//   dh = dir*2 + half; chunk = i*8+w (i<6) or 48+w (i==6, w<2);
//   lane = b + 16*lhi;  cell: b, hcol = 32i + 4w + lhi; g = gate.
// ---------------------------------------------------------------------------
__global__ __launch_bounds__(512) void xwih_kernel(
    const float* __restrict__ x, const unsigned short* __restrict__ wih_hi,
    const unsigned short* __restrict__ wih_lo, const float* __restrict__ b_l,
    const float* __restrict__ b_r, float* __restrict__ pre) {
  int bid = blockIdx.x;             // 640 = 2 * 64 * 5
  int dir = (bid >= 320) ? 1 : 0;
  int rem = bid - dir * 320;
  int rbm = rem / 5, nb = rem - rbm * 5;
  int m0 = rbm * 128, n0 = nb * 160;
  int tid = threadIdx.x, w = tid >> 6, l = tid & 63;
  int lrow = l & 15, lk8 = (l >> 4) << 3;
  const float* xd = x + (size_t)dir * 8192 * LIN;
  const unsigned short* wh = wih_hi + (size_t)dir * 179200;
  const unsigned short* wl = wih_lo + (size_t)dir * 179200;
  const float* bias = dir ? b_r : b_l;

  f32x4v acc[10];
  #pragma unroll
  for (int i = 0; i < 10; ++i) acc[i] = (f32x4v){0.f, 0.f, 0.f, 0.f};

  int row = m0 + w * 16 + lrow;
  for (int kt = 0; kt < 7; ++kt) {
    int kb = kt * 32 + lk8;
    bfrag8 ah = {0,0,0,0,0,0,0,0}, al = {0,0,0,0,0,0,0,0};
    if (kb <= 192) {
      const float* fp = xd + (size_t)row * LIN + kb;
      float4 v0 = *reinterpret_cast<const float4*>(fp);
      float4 v1 = *reinterpret_cast<const float4*>(fp + 4);
      mk_hilo(v0, v1, ah, al);
    }
    #pragma unroll
    for (int nt = 0; nt < 10; ++nt) {
      int ntg = nb * 10 + nt;
      size_t fo = ((size_t)(ntg * 7 + kt) * 64 + l) * 8;
      bfrag8 bh = *reinterpret_cast<const bfrag8*>(wh + fo);
      bfrag8 bl = *reinterpret_cast<const bfrag8*>(wl + fo);
      acc[nt] = __builtin_amdgcn_mfma_f32_16x16x32_bf16(ah, bh, acc[nt], 0, 0, 0);
      acc[nt] = __builtin_amdgcn_mfma_f32_16x16x32_bf16(al, bh, acc[nt], 0, 0, 0);
      acc[nt] = __builtin_amdgcn_mfma_f32_16x16x32_bf16(ah, bl, acc[nt], 0, 0, 0);
    }
  }
  #pragma unroll
  for (int nt = 0; nt < 10; ++nt) {
    int n = n0 + nt * 16 + lrow;                    // permuted col n'
    float bb = bias[(n & 3) * 200 + (n >> 2)];      // original bias row
    int hcol = n >> 2, g = n & 3;
    int i6 = hcol >> 5;                             // 0..6
    int hc5 = hcol & 31;
    int wv = hc5 >> 2, lhi = hc5 & 3;
    int chunk = (i6 < 6) ? (i6 * 8 + wv) : (48 + wv);
    #pragma unroll
    for (int rr = 0; rr < 4; ++rr) {
      int r2 = m0 + w * 16 + ((l >> 4) << 2) + rr;  // global row = t*32 + b32
      int t = r2 >> 5, b32 = r2 & 31;
      int hf2 = b32 >> 4, b = b32 & 15;
      int lane = b + 16 * lhi;
      size_t dst = ((((size_t)(dir * 2 + hf2) * 256 + t) * 50 + chunk) * 64 + lane) * 4 + g;
      pre[dst] = acc[nt][rr] + bb;
    }
  }
}

// ---------------------------------------------------------------------------
// Kernel R: recurrence, 4 blocks = (dir, batch-half), 512 thr, M=16.
// gates^T = Whh' @ h^T; cell fully in-register. 48 of 50 Whh' tiles
// register-resident (Breg[6][7]); only tiles 48,49 in LDS (read by w<2).
// acc is initialized from the pre-gates (bias+Wih term) so MFMA adds onto it.
// Fused cell: 5 exp2 + 2 rcp per cell (shared denominators), args clamped.
// ---------------------------------------------------------------------------
__global__ __launch_bounds__(512, 2) void lstm_kernel(
    const float* __restrict__ pre, const float* __restrict__ Whh_l,
    const float* __restrict__ Whh_r, float* __restrict__ out) {
  __shared__ __align__(16) unsigned short hbufA[3584];   // [kt:7][lane:64][j:8] bf16
  __shared__ __align__(16) unsigned short hbufB[3584];
  __shared__ __align__(16) unsigned short whx[7168];     // tiles 48,49 A-frags

  int bi = blockIdx.x;
  int dir = bi >> 1, half = bi & 1;
  const float* Whh = dir ? Whh_r : Whh_l;
  int tid = threadIdx.x, w = tid >> 6, l = tid & 63;
  int lrow = l & 15, lk8 = (l >> 4) << 3;

  // --- register-resident Whh' A-frags: tiles tau = w + 8i, i<6 (0..47) ---
  bfrag8 Breg[6][7];
  #pragma unroll
  for (int i = 0; i < 6; ++i) {
    int np = (w + 8 * i) * 16 + lrow;
    int no = (np & 3) * 200 + (np >> 2);
    #pragma unroll
    for (int kt = 0; kt < 7; ++kt) {
      int kb = kt * 32 + lk8;
      bfrag8 bb = {0,0,0,0,0,0,0,0};
      if (kb <= 192) {
        const float* fp = Whh + (size_t)no * HD + kb;
        bb = mk_hi(*reinterpret_cast<const float4*>(fp),
                   *reinterpret_cast<const float4*>(fp + 4));
      }
      Breg[i][kt] = bb;
    }
  }
  // --- LDS tiles 48,49 ---
  for (int e = tid; e < 896; e += 512) {
    int l2 = e & 63, f = e >> 6;          // f = tile*7 + kt, f<14
    int kt = f % 7, tile = f / 7;
    int np = (48 + tile) * 16 + (l2 & 15);
    int no = (np & 3) * 200 + (np >> 2);
    int kb = kt * 32 + ((l2 >> 4) << 3);
    bfrag8 bb = {0,0,0,0,0,0,0,0};
    if (kb <= 192) {
      const float* fp = Whh + (size_t)no * HD + kb;
      bb = mk_hi(*reinterpret_cast<const float4*>(fp),
                 *reinterpret_cast<const float4*>(fp + 4));
    }
    *reinterpret_cast<bfrag8*>(&whx[(size_t)e * 8]) = bb;
  }
  // zero h buffers (h0 = 0; K-pad positions stay zero forever)
  for (int e = tid; e < 896; e += 512) {
    reinterpret_cast<uint64_t*>(hbufA)[e] = 0;
    reinterpret_cast<uint64_t*>(hbufB)[e] = 0;
  }
  float c[7];
  #pragma unroll
  for (int i = 0; i < 7; ++i) c[i] = 0.f;

  // h-frag write slot (bf16, MFMA B layout); kt handled by +i*512
  int hbase = 4 * w + (l >> 4);                       // hcol mod 32
  int hw = (lrow + 16 * ((hbase >> 3) & 3)) * 8 + (hbase & 7);

  // pre: contiguous per (dh, t); per-lane base covers chunks w+8i and 48+w
  const float* psrcL = pre + ((size_t)(dir * 2 + half) * 256 + (dir ? 255 : 0)) * 12800
                     + w * 256 + (l << 2);
  const int pstep = dir ? -12800 : 12800;
  float* outp = out + (size_t)((half * 16 + lrow) * 256 + (dir ? 255 : 0)) * 400
              + dir * 200 + (l >> 4) + 4 * w;
  const int ostep = dir ? -400 : 400;

  __syncthreads();

  // prefetch pre for step 0 into pA
  float4 pA[7], pB[7];
  #pragma unroll
  for (int i = 0; i < 7; ++i) {
    pA[i] = make_float4(0.f, 0.f, 0.f, 0.f);
    pB[i] = make_float4(0.f, 0.f, 0.f, 0.f);
  }
  #pragma unroll
  for (int i = 0; i < 6; ++i) pA[i] = *reinterpret_cast<const float4*>(psrcL + i * 2048);
  if (w < 2) pA[6] = *reinterpret_cast<const float4*>(psrcL + 12288);
  psrcL += pstep;

  const float NL  = -1.4426950408889634f;   // -log2(e)
  const float N2L = -2.8853900817779268f;   // -2*log2(e)

  auto STEP = [&](const unsigned short* rbuf, unsigned short* wbuf,
                  float4 (&pc)[7], float4 (&pn)[7]) {
    // --- A: issue next-step pre loads (contiguous block; first in vm queue) ---
    #pragma unroll
    for (int i = 0; i < 6; ++i) pn[i] = *reinterpret_cast<const float4*>(psrcL + i * 2048);
    if (w < 2) pn[6] = *reinterpret_cast<const float4*>(psrcL + 12288);
    psrcL += pstep;
    // --- C: MFMA phase; acc starts at pre-gates (bias + x@Wih term) ---
    f32x4v acc[7];
    #pragma unroll
    for (int i = 0; i < 7; ++i)
      acc[i] = (f32x4v){pc[i].x, pc[i].y, pc[i].z, pc[i].w};
    #pragma unroll
    for (int kt = 0; kt < 7; ++kt) {
      bfrag8 hf = *reinterpret_cast<const bfrag8*>(&rbuf[kt * 512 + l * 8]);
      #pragma unroll
      for (int i = 0; i < 6; ++i)
        acc[i] = __builtin_amdgcn_mfma_f32_16x16x32_bf16(Breg[i][kt], hf, acc[i], 0, 0, 0);
      if (w < 2) {
        bfrag8 b6 = *reinterpret_cast<const bfrag8*>(&whx[(w * 7 + kt) * 512 + l * 8]);
        acc[6] = __builtin_amdgcn_mfma_f32_16x16x32_bf16(b6, hf, acc[6], 0, 0, 0);
      }
    }
    // --- D: fused cell (lane owns b=l&15, hcol=4w+(l>>4)+32i) + stores ---
    #pragma unroll
    for (int i = 0; i < 7; ++i) {
      if (i < 6 || w < 2) {
        float ig = acc[i][0];
        float fg = acc[i][1];
        float gg = acc[i][2];
        float og = acc[i][3];
        float u  = __builtin_amdgcn_exp2f(clamp40(fg * NL));
        float v  = __builtin_amdgcn_exp2f(clamp40(ig * NL));
        float Wt = __builtin_amdgcn_exp2f(clamp40(gg * N2L));
        float y  = __builtin_amdgcn_exp2f(clamp40(og * NL));
        float pu = 1.f + u, pv = 1.f + v, pw = 1.f + Wt, py = 1.f + y;
        float P  = pv * pw;
        float r1 = __builtin_amdgcn_rcpf(pu * P);
        float cn = (c[i] * P + pu * (1.f - Wt)) * r1;
        c[i] = cn;
        float Z  = __builtin_amdgcn_exp2f(clamp40(cn * N2L));
        float h  = (1.f - Z) * __builtin_amdgcn_rcpf(py * (1.f + Z));
        outp[32 * i] = h;
        wbuf[hw + i * 512] = f2bf(h);
      }
    }
    outp += ostep;
    // --- E: barrier; memory pinned, reg-only ops may cross ---
    __builtin_amdgcn_sched_barrier(0x1 | 0x2 | 0x4 | 0x8);
    asm volatile("s_waitcnt lgkmcnt(0)");
    __builtin_amdgcn_s_barrier();
    __builtin_amdgcn_sched_barrier(0x1 | 0x2 | 0x4 | 0x8);
  };

  for (int it = 0; it < 128; ++it) {
    STEP(hbufA, hbufB, pA, pB);
    STEP(hbufB, hbufA, pB, pA);
  }
}

// ---------------------------------------------------------------------------
extern "C" void kernel_launch(void* const* d_in, const int* in_sizes, int n_in,
                              void* d_out, int out_size, void* d_ws, size_t ws_size,
                              hipStream_t stream) {
  (void)in_sizes; (void)n_in; (void)out_size; (void)ws_size;
  const int* chars        = (const int*)d_in[0];
  const int* left_bichar  = (const int*)d_in[1];
  const int* right_bichar = (const int*)d_in[2];
  const int* extchars     = (const int*)d_in[3];
  const int* extleft      = (const int*)d_in[4];
  const int* extright     = (const int*)d_in[5];
  const int* ctype        = (const int*)d_in[6];
  const float* E_char      = (const float*)d_in[7];
  const float* E_extchar   = (const float*)d_in[8];
  const float* E_bichar    = (const float*)d_in[9];
  const float* E_extbichar = (const float*)d_in[10];
  const float* E_ctype     = (const float*)d_in[11];
  const float* fc_w  = (const float*)d_in[12];
  const float* fc_b  = (const float*)d_in[13];
  const float* Wih_l = (const float*)d_in[14];
  const float* Whh_l = (const float*)d_in[15];
  const float* b_l   = (const float*)d_in[16];
  const float* Wih_r = (const float*)d_in[17];
  const float* Whh_r = (const float*)d_in[18];
  const float* b_r   = (const float*)d_in[19];
  float* out = (float*)d_out;
  char* ws = (char*)d_ws;

  float* x   = (float*)(ws);                        // 13,107,200 B
  float* pre = (float*)(ws + 13107200);             // 52,428,800 B
  unsigned short* fcw_hi = (unsigned short*)(ws + 65536000);   // 186,368
  unsigned short* fcw_lo = (unsigned short*)(ws + 65722368);   // 186,368
  unsigned short* wih_hi = (unsigned short*)(ws + 65908736);   // 716,800
  unsigned short* wih_lo = (unsigned short*)(ws + 66625536);   // 716,800

  presplit_kernel<<<256, 256, 0, stream>>>(fc_w, Wih_l, Wih_r, fcw_hi, fcw_lo, wih_hi, wih_lo);
  fc_kernel<<<512, 256, 0, stream>>>(chars, left_bichar, right_bichar, extchars,
                                     extleft, extright, ctype, E_char, E_extchar,
                                     E_bichar, E_extbichar, E_ctype, fc_b,
                                     fcw_hi, fcw_lo, x);
  xwih_kernel<<<640, 512, 0, stream>>>(x, wih_hi, wih_lo, b_l, b_r, pre);
  lstm_kernel<<<4, 512, 0, stream>>>(pre, Whh_l, Whh_r, out);
}